// Round 1
// baseline (740.024 us; speedup 1.0000x reference)
//
#include <hip/hip_runtime.h>

typedef float f32x4 __attribute__((ext_vector_type(4)));
typedef short bf16x8 __attribute__((ext_vector_type(8)));
typedef unsigned short u16;
typedef unsigned int u32;

// float -> bf16 bits, round-to-nearest-even
__device__ __forceinline__ u16 f2b(float f) {
    union { float f; u32 u; } v; v.f = f;
    u32 r = v.u + 0x7fffu + ((v.u >> 16) & 1u);
    return (u16)(r >> 16);
}

// shifted softplus: log(1+e^x) - log(2), numerically stable
__device__ __forceinline__ float ssp(float x) {
    return fmaxf(x, 0.0f) + log1pf(__expf(-fabsf(x))) - 0.6931471805599453f;
}

// ---------------------------------------------------------------------------
// Convert all weight matrices to bf16, layout [out_c][k] (fw1 K-padded 50->64)
// ws layout (u16 elements): fw1b[128*64] | fw2b[128*128] | w1b | w2b | w3b
// ---------------------------------------------------------------------------
__global__ void prep_weights(const float* __restrict__ fw1,
                             const float* __restrict__ fw2,
                             const float* __restrict__ w1,
                             const float* __restrict__ w2,
                             const float* __restrict__ w3,
                             u16* __restrict__ out) {
    int t = blockIdx.x * blockDim.x + threadIdx.x;
    if (t < 128 * 64) {                      // fw1: [128][50] -> [128][64] pad
        int c = t >> 6, k = t & 63;
        out[t] = f2b(k < 50 ? fw1[c * 50 + k] : 0.0f);
        return;
    }
    t -= 128 * 64;
    if (t < 16384) { out[8192 + t] = f2b(fw2[t]); return; }
    t -= 16384;
    if (t < 16384) { out[8192 + 16384 + t] = f2b(w1[t]); return; }
    t -= 16384;
    if (t < 16384) { out[8192 + 32768 + t] = f2b(w2[t]); return; }
    t -= 16384;
    if (t < 16384) { out[8192 + 49152 + t] = f2b(w3[t]); return; }
}

// ---------------------------------------------------------------------------
// Generic out = act(in[M,128] @ wT + bias), bf16 MFMA 16x16x32.
// 256 threads (4 waves), 64 rows/block; wave w owns rows w*16..w*16+15.
// ---------------------------------------------------------------------------
template <int ACT>
__global__ __launch_bounds__(256, 3) void linear128(
    const float* __restrict__ in, const u16* __restrict__ wb,
    const float* __restrict__ bias, float* __restrict__ out, int M) {
    __shared__ u16 in_lds[64 * 136];   // rows stride 136 (16B-aligned, conflict-light)
    __shared__ u16 w_lds[128 * 136];

    const int tid = threadIdx.x;
    const int r0 = blockIdx.x * 64;

    // stage weights (bf16, 16B chunks)
    for (int idx = tid; idx < 128 * 16; idx += 256) {
        int c = idx >> 4, kc = (idx & 15) * 8;
        *reinterpret_cast<uint4*>(&w_lds[c * 136 + kc]) =
            *reinterpret_cast<const uint4*>(&wb[c * 128 + kc]);
    }
    // stage input rows f32 -> bf16 (float4 loads)
    for (int idx = tid; idx < 64 * 32; idx += 256) {
        int r = idx >> 5, kc = (idx & 31) * 4;
        int row = r0 + r;
        float4 v = make_float4(0.f, 0.f, 0.f, 0.f);
        if (row < M) v = *reinterpret_cast<const float4*>(&in[(size_t)row * 128 + kc]);
        u16* p = &in_lds[r * 136 + kc];
        p[0] = f2b(v.x); p[1] = f2b(v.y); p[2] = f2b(v.z); p[3] = f2b(v.w);
    }
    __syncthreads();

    const int l = tid & 63, w = tid >> 6;
    const int lr = l & 15, lg = l >> 4;

    f32x4 acc[8] = {};
    for (int ks = 0; ks < 4; ++ks) {
        bf16x8 a = *reinterpret_cast<const bf16x8*>(
            &in_lds[(w * 16 + lr) * 136 + ks * 32 + lg * 8]);
        for (int n = 0; n < 8; ++n) {
            bf16x8 b = *reinterpret_cast<const bf16x8*>(
                &w_lds[(n * 16 + lr) * 136 + ks * 32 + lg * 8]);
            acc[n] = __builtin_amdgcn_mfma_f32_16x16x32_bf16(a, b, acc[n], 0, 0, 0);
        }
    }

    for (int n = 0; n < 8; ++n) {
        int c = n * 16 + lr;
        float bv = bias ? bias[c] : 0.0f;
        for (int i = 0; i < 4; ++i) {
            int row = r0 + w * 16 + lg * 4 + i;
            if (row < M) {
                float v = acc[n][i] + bv;
                if (ACT) v = ssp(v);
                out[(size_t)row * 128 + c] = v;
            }
        }
    }
}

// ---------------------------------------------------------------------------
// Fused edge kernel: 64 edges/block.
//   h = ssp(basis @ fw1T + fb1)            GEMM1 (K padded to 64)
//   W = (h @ fw2T + fb2) * C(e_ji)         GEMM2 (K=128)
//   atomicAdd(agg[dst], xh[src] * W)
// ---------------------------------------------------------------------------
__global__ __launch_bounds__(256, 2) void edge_kernel(
    const float* __restrict__ basis, const float* __restrict__ e_ji,
    const int* __restrict__ pairs, const float* __restrict__ xh,
    const u16* __restrict__ fw1b, const u16* __restrict__ fw2b,
    const float* __restrict__ fb1, const float* __restrict__ fb2,
    float* __restrict__ agg, int E) {
    __shared__ u16 hb[64 * 136];        // basis tile (stride 72) then h (stride 136)
    __shared__ u16 fw1_lds[128 * 72];
    __shared__ u16 fw2_lds[128 * 136];
    __shared__ float cc[64];
    __shared__ int s_src[64];
    __shared__ int s_dst[64];

    const int tid = threadIdx.x;
    const int e0 = blockIdx.x * 64;

    // stage fw1 bf16 [128][64] -> stride 72
    for (int idx = tid; idx < 128 * 8; idx += 256) {
        int c = idx >> 3, kc = (idx & 7) * 8;
        *reinterpret_cast<uint4*>(&fw1_lds[c * 72 + kc]) =
            *reinterpret_cast<const uint4*>(&fw1b[c * 64 + kc]);
    }
    // stage fw2 bf16 [128][128] -> stride 136
    for (int idx = tid; idx < 128 * 16; idx += 256) {
        int c = idx >> 4, kc = (idx & 15) * 8;
        *reinterpret_cast<uint4*>(&fw2_lds[c * 136 + kc]) =
            *reinterpret_cast<const uint4*>(&fw2b[c * 128 + kc]);
    }
    // stage basis tile f32 -> bf16, rows stride 72, K-pad 50->64 with zeros
    for (int idx = tid; idx < 64 * 64; idx += 256) {
        int e = idx >> 6, k = idx & 63;
        int eg = e0 + e;
        float v = (k < 50 && eg < E) ? basis[(size_t)eg * 50 + k] : 0.0f;
        hb[e * 72 + k] = f2b(v);
    }
    if (tid < 64) {
        int eg = e0 + tid;
        if (eg < E) {
            cc[tid] = 0.25f * (__cosf(e_ji[eg] * 0.31415926535897932f) + 1.0f);
            s_src[tid] = pairs[eg];
            s_dst[tid] = pairs[E + eg];
        } else {
            cc[tid] = 0.0f; s_src[tid] = 0; s_dst[tid] = 0;
        }
    }
    __syncthreads();

    const int l = tid & 63, w = tid >> 6;
    const int lr = l & 15, lg = l >> 4;

    // GEMM1: h_pre = basis @ fw1T   (M=16/wave, N=128, K=64)
    f32x4 acc1[8] = {};
    for (int ks = 0; ks < 2; ++ks) {
        bf16x8 a = *reinterpret_cast<const bf16x8*>(
            &hb[(w * 16 + lr) * 72 + ks * 32 + lg * 8]);
        for (int n = 0; n < 8; ++n) {
            bf16x8 b = *reinterpret_cast<const bf16x8*>(
                &fw1_lds[(n * 16 + lr) * 72 + ks * 32 + lg * 8]);
            acc1[n] = __builtin_amdgcn_mfma_f32_16x16x32_bf16(a, b, acc1[n], 0, 0, 0);
        }
    }
    __syncthreads();   // all waves done reading basis region

    // h = ssp(acc1 + fb1) -> hb as bf16, stride 136
    // C/D layout: col = lane&15, row = (lane>>4)*4 + i   [m89]
    for (int n = 0; n < 8; ++n) {
        int c = n * 16 + lr;
        float bv = fb1[c];
        for (int i = 0; i < 4; ++i) {
            int r = w * 16 + lg * 4 + i;
            hb[r * 136 + c] = f2b(ssp(acc1[n][i] + bv));
        }
    }
    __syncthreads();

    // GEMM2: W_pre = h @ fw2T   (K=128)
    f32x4 acc2[8] = {};
    for (int ks = 0; ks < 4; ++ks) {
        bf16x8 a = *reinterpret_cast<const bf16x8*>(
            &hb[(w * 16 + lr) * 136 + ks * 32 + lg * 8]);
        for (int n = 0; n < 8; ++n) {
            bf16x8 b = *reinterpret_cast<const bf16x8*>(
                &fw2_lds[(n * 16 + lr) * 136 + ks * 32 + lg * 8]);
            acc2[n] = __builtin_amdgcn_mfma_f32_16x16x32_bf16(a, b, acc2[n], 0, 0, 0);
        }
    }

    // epilogue: W = (acc2 + fb2) * cc; val = xh[src]*W; agg[dst] += val
    for (int n = 0; n < 8; ++n) {
        int c = n * 16 + lr;
        float bv = fb2[c];
        for (int i = 0; i < 4; ++i) {
            int eloc = w * 16 + lg * 4 + i;
            if (e0 + eloc < E) {
                float Wv = (acc2[n][i] + bv) * cc[eloc];
                float val = xh[(size_t)s_src[eloc] * 128 + c] * Wv;
                unsafeAtomicAdd(&agg[(size_t)s_dst[eloc] * 128 + c], val);
            }
        }
    }
}

extern "C" void kernel_launch(void* const* d_in, const int* in_sizes, int n_in,
                              void* d_out, int out_size, void* d_ws, size_t ws_size,
                              hipStream_t stream) {
    const float* x      = (const float*)d_in[0];
    const int*   pairs  = (const int*)d_in[1];
    const float* e_ji   = (const float*)d_in[2];
    const float* basis  = (const float*)d_in[3];
    const float* fw1    = (const float*)d_in[4];
    const float* fb1    = (const float*)d_in[5];
    const float* fw2    = (const float*)d_in[6];
    const float* fb2    = (const float*)d_in[7];
    const float* w1     = (const float*)d_in[8];
    const float* w2     = (const float*)d_in[9];
    const float* b2     = (const float*)d_in[10];
    const float* w3     = (const float*)d_in[11];
    const float* b3     = (const float*)d_in[12];
    float* out = (float*)d_out;

    const int N = in_sizes[0] / 128;
    const int E = in_sizes[2];
    const size_t nodeBytes = (size_t)N * 128 * sizeof(float);

    char* ws = (char*)d_ws;
    float* xh  = (float*)ws;                       // [N,128] f32
    float* agg = (float*)(ws + nodeBytes);         // [N,128] f32
    u16*   wb  = (u16*)(ws + 2 * nodeBytes);       // bf16 weights
    const u16* fw1b = wb;                          //  8192
    const u16* fw2b = wb + 8192;                   // 16384
    const u16* w1b  = wb + 8192 + 16384;
    const u16* w2b  = wb + 8192 + 32768;
    const u16* w3b  = wb + 8192 + 49152;

    prep_weights<<<288, 256, 0, stream>>>(fw1, fw2, w1, w2, w3, wb);
    hipMemsetAsync(agg, 0, nodeBytes, stream);

    const int nodeBlocks = (N + 63) / 64;
    // xh = x @ w1^T
    linear128<0><<<nodeBlocks, 256, 0, stream>>>(x, w1b, nullptr, xh, N);
    // fused filter MLP + modulate + gather + scatter
    edge_kernel<<<(E + 63) / 64, 256, 0, stream>>>(basis, e_ji, pairs, xh,
                                                   fw1b, fw2b, fb1, fb2, agg, E);
    // out = ssp(agg @ w2^T + b2)
    linear128<1><<<nodeBlocks, 256, 0, stream>>>(agg, w2b, b2, out, N);
    // out = out @ w3^T + b3   (in-place: block stages its rows to LDS first)
    linear128<0><<<nodeBlocks, 256, 0, stream>>>(out, w3b, b3, out, N);
}

// Round 2
// 651.048 us; speedup vs baseline: 1.1367x; 1.1367x over previous
//
#include <hip/hip_runtime.h>

typedef float f32x4 __attribute__((ext_vector_type(4)));
typedef short bf16x8 __attribute__((ext_vector_type(8)));
typedef unsigned short u16;
typedef unsigned int u32;

// float -> bf16 bits, round-to-nearest-even
__device__ __forceinline__ u16 f2b(float f) {
    union { float f; u32 u; } v; v.f = f;
    u32 r = v.u + 0x7fffu + ((v.u >> 16) & 1u);
    return (u16)(r >> 16);
}
__device__ __forceinline__ float b2f_lo(u32 p) { // low u16 -> float
    union { u32 u; float f; } v; v.u = p << 16; return v.f;
}
__device__ __forceinline__ float b2f_hi(u32 p) { // high u16 -> float
    union { u32 u; float f; } v; v.u = p & 0xffff0000u; return v.f;
}

// shifted softplus: log(1+e^x) - log(2), numerically stable
__device__ __forceinline__ float ssp(float x) {
    return fmaxf(x, 0.0f) + log1pf(__expf(-fabsf(x))) - 0.6931471805599453f;
}

// ---------------------------------------------------------------------------
// Convert all weight matrices to bf16, layout [out_c][k] (fw1 K-padded 50->64)
// ---------------------------------------------------------------------------
__global__ void prep_weights(const float* __restrict__ fw1,
                             const float* __restrict__ fw2,
                             const float* __restrict__ w1,
                             const float* __restrict__ w2,
                             const float* __restrict__ w3,
                             u16* __restrict__ out) {
    int t = blockIdx.x * blockDim.x + threadIdx.x;
    if (t < 128 * 64) {                      // fw1: [128][50] -> [128][64] pad
        int c = t >> 6, k = t & 63;
        out[t] = f2b(k < 50 ? fw1[c * 50 + k] : 0.0f);
        return;
    }
    t -= 128 * 64;
    if (t < 16384) { out[8192 + t] = f2b(fw2[t]); return; }
    t -= 16384;
    if (t < 16384) { out[8192 + 16384 + t] = f2b(w1[t]); return; }
    t -= 16384;
    if (t < 16384) { out[8192 + 32768 + t] = f2b(w2[t]); return; }
    t -= 16384;
    if (t < 16384) { out[8192 + 49152 + t] = f2b(w3[t]); return; }
}

// ---------------------------------------------------------------------------
// Generic out = act(in[M,128] @ wT + bias), bf16 MFMA 16x16x32.
// OBF=1 -> write bf16 (u16) output, else f32.
// ---------------------------------------------------------------------------
template <int ACT, int OBF>
__global__ __launch_bounds__(256, 3) void linear128(
    const float* __restrict__ in, const u16* __restrict__ wb,
    const float* __restrict__ bias, void* __restrict__ outv, int M) {
    __shared__ u16 in_lds[64 * 136];
    __shared__ u16 w_lds[128 * 136];

    const int tid = threadIdx.x;
    const int r0 = blockIdx.x * 64;

    for (int idx = tid; idx < 128 * 16; idx += 256) {
        int c = idx >> 4, kc = (idx & 15) * 8;
        *reinterpret_cast<uint4*>(&w_lds[c * 136 + kc]) =
            *reinterpret_cast<const uint4*>(&wb[c * 128 + kc]);
    }
    for (int idx = tid; idx < 64 * 32; idx += 256) {
        int r = idx >> 5, kc = (idx & 31) * 4;
        int row = r0 + r;
        float4 v = make_float4(0.f, 0.f, 0.f, 0.f);
        if (row < M) v = *reinterpret_cast<const float4*>(&in[(size_t)row * 128 + kc]);
        u16* p = &in_lds[r * 136 + kc];
        p[0] = f2b(v.x); p[1] = f2b(v.y); p[2] = f2b(v.z); p[3] = f2b(v.w);
    }
    __syncthreads();

    const int l = tid & 63, w = tid >> 6;
    const int lr = l & 15, lg = l >> 4;

    f32x4 acc[8] = {};
    for (int ks = 0; ks < 4; ++ks) {
        bf16x8 a = *reinterpret_cast<const bf16x8*>(
            &in_lds[(w * 16 + lr) * 136 + ks * 32 + lg * 8]);
        for (int n = 0; n < 8; ++n) {
            bf16x8 b = *reinterpret_cast<const bf16x8*>(
                &w_lds[(n * 16 + lr) * 136 + ks * 32 + lg * 8]);
            acc[n] = __builtin_amdgcn_mfma_f32_16x16x32_bf16(a, b, acc[n], 0, 0, 0);
        }
    }

    for (int n = 0; n < 8; ++n) {
        int c = n * 16 + lr;
        float bv = bias ? bias[c] : 0.0f;
        for (int i = 0; i < 4; ++i) {
            int row = r0 + w * 16 + lg * 4 + i;
            if (row < M) {
                float v = acc[n][i] + bv;
                if (ACT) v = ssp(v);
                if (OBF) ((u16*)outv)[(size_t)row * 128 + c] = f2b(v);
                else     ((float*)outv)[(size_t)row * 128 + c] = v;
            }
        }
    }
}

// ---------------------------------------------------------------------------
// Edge filter MLP only: Wb[e] = (ssp(basis@fw1T+fb1)@fw2T+fb2)*C(e)  (bf16)
// ---------------------------------------------------------------------------
__global__ __launch_bounds__(256, 2) void edge_mlp(
    const float* __restrict__ basis, const float* __restrict__ e_ji,
    const u16* __restrict__ fw1b, const u16* __restrict__ fw2b,
    const float* __restrict__ fb1, const float* __restrict__ fb2,
    u16* __restrict__ Wb, int E) {
    __shared__ u16 hb[64 * 136];
    __shared__ u16 fw1_lds[128 * 72];
    __shared__ u16 fw2_lds[128 * 136];
    __shared__ float cc[64];

    const int tid = threadIdx.x;
    const int e0 = blockIdx.x * 64;

    for (int idx = tid; idx < 128 * 8; idx += 256) {
        int c = idx >> 3, kc = (idx & 7) * 8;
        *reinterpret_cast<uint4*>(&fw1_lds[c * 72 + kc]) =
            *reinterpret_cast<const uint4*>(&fw1b[c * 64 + kc]);
    }
    for (int idx = tid; idx < 128 * 16; idx += 256) {
        int c = idx >> 4, kc = (idx & 15) * 8;
        *reinterpret_cast<uint4*>(&fw2_lds[c * 136 + kc]) =
            *reinterpret_cast<const uint4*>(&fw2b[c * 128 + kc]);
    }
    for (int idx = tid; idx < 64 * 64; idx += 256) {
        int e = idx >> 6, k = idx & 63;
        int eg = e0 + e;
        float v = (k < 50 && eg < E) ? basis[(size_t)eg * 50 + k] : 0.0f;
        hb[e * 72 + k] = f2b(v);
    }
    if (tid < 64) {
        int eg = e0 + tid;
        cc[tid] = (eg < E)
            ? 0.25f * (__cosf(e_ji[eg] * 0.31415926535897932f) + 1.0f) : 0.0f;
    }
    __syncthreads();

    const int l = tid & 63, w = tid >> 6;
    const int lr = l & 15, lg = l >> 4;

    // GEMM1
    f32x4 acc1[8] = {};
    for (int ks = 0; ks < 2; ++ks) {
        bf16x8 a = *reinterpret_cast<const bf16x8*>(
            &hb[(w * 16 + lr) * 72 + ks * 32 + lg * 8]);
        for (int n = 0; n < 8; ++n) {
            bf16x8 b = *reinterpret_cast<const bf16x8*>(
                &fw1_lds[(n * 16 + lr) * 72 + ks * 32 + lg * 8]);
            acc1[n] = __builtin_amdgcn_mfma_f32_16x16x32_bf16(a, b, acc1[n], 0, 0, 0);
        }
    }
    __syncthreads();   // basis region dead; safe to write h at stride 136

    for (int n = 0; n < 8; ++n) {
        int c = n * 16 + lr;
        float bv = fb1[c];
        for (int i = 0; i < 4; ++i) {
            int r = w * 16 + lg * 4 + i;
            hb[r * 136 + c] = f2b(ssp(acc1[n][i] + bv));
        }
    }
    __syncthreads();

    // GEMM2
    f32x4 acc2[8] = {};
    for (int ks = 0; ks < 4; ++ks) {
        bf16x8 a = *reinterpret_cast<const bf16x8*>(
            &hb[(w * 16 + lr) * 136 + ks * 32 + lg * 8]);
        for (int n = 0; n < 8; ++n) {
            bf16x8 b = *reinterpret_cast<const bf16x8*>(
                &fw2_lds[(n * 16 + lr) * 136 + ks * 32 + lg * 8]);
            acc2[n] = __builtin_amdgcn_mfma_f32_16x16x32_bf16(a, b, acc2[n], 0, 0, 0);
        }
    }

    // W = (acc2 + fb2) * cc -> bf16 into hb (per-wave own rows, in-order LDS)
    for (int n = 0; n < 8; ++n) {
        int c = n * 16 + lr;
        float bv = fb2[c];
        for (int i = 0; i < 4; ++i) {
            int eloc = w * 16 + lg * 4 + i;
            hb[eloc * 136 + c] = f2b((acc2[n][i] + bv) * cc[eloc]);
        }
    }
    __syncthreads();

    // cooperative coalesced store: 64 rows x 256B
    for (int idx = tid; idx < 64 * 16; idx += 256) {
        int row = idx >> 4, chunk = idx & 15;
        if (e0 + row < E) {
            *reinterpret_cast<uint4*>(&Wb[(size_t)(e0 + row) * 128 + chunk * 8]) =
                *reinterpret_cast<const uint4*>(&hb[row * 136 + chunk * 8]);
        }
    }
}

// ---------------------------------------------------------------------------
// CSR build: histogram -> scan -> fill
// ---------------------------------------------------------------------------
__global__ void hist_kernel(const int* __restrict__ pairs, int* __restrict__ deg, int E) {
    int e = blockIdx.x * blockDim.x + threadIdx.x;
    if (e < E) atomicAdd(&deg[pairs[E + e]], 1);
}

__global__ void scan_a(const int* __restrict__ deg, int* __restrict__ incl,
                       int* __restrict__ bsum, int N) {
    __shared__ int s[256];
    int i = blockIdx.x * 256 + threadIdx.x;
    int v = (i < N) ? deg[i] : 0;
    s[threadIdx.x] = v; __syncthreads();
    for (int off = 1; off < 256; off <<= 1) {
        int t = (threadIdx.x >= off) ? s[threadIdx.x - off] : 0;
        __syncthreads();
        s[threadIdx.x] += t; __syncthreads();
    }
    if (i < N) incl[i] = s[threadIdx.x];
    if (threadIdx.x == 255) bsum[blockIdx.x] = s[255];
}

__global__ void scan_b(int* __restrict__ bsum, int nb) {
    __shared__ int s[256];
    int v = (threadIdx.x < nb) ? bsum[threadIdx.x] : 0;
    s[threadIdx.x] = v; __syncthreads();
    for (int off = 1; off < 256; off <<= 1) {
        int t = (threadIdx.x >= off) ? s[threadIdx.x - off] : 0;
        __syncthreads();
        s[threadIdx.x] += t; __syncthreads();
    }
    if (threadIdx.x < nb) bsum[threadIdx.x] = s[threadIdx.x] - v;  // exclusive
}

__global__ void scan_c(const int* __restrict__ incl, const int* __restrict__ deg,
                       const int* __restrict__ bsum, int* __restrict__ rowst,
                       int* __restrict__ cursor, int N) {
    int i = blockIdx.x * 256 + threadIdx.x;
    if (i < N) {
        int r = incl[i] - deg[i] + bsum[blockIdx.x];
        rowst[i] = r; cursor[i] = r;
    }
}

__global__ void fill_kernel(const int* __restrict__ pairs, int* __restrict__ cursor,
                            int* __restrict__ eidw, int* __restrict__ esrc, int E) {
    int e = blockIdx.x * blockDim.x + threadIdx.x;
    if (e < E) {
        int s = pairs[e], d = pairs[E + e];
        int pos = atomicAdd(&cursor[d], 1);
        eidw[pos] = e; esrc[pos] = s;
    }
}

// ---------------------------------------------------------------------------
// Aggregate: one wave per node, 2 cols/lane, register accumulation.
// ---------------------------------------------------------------------------
__global__ __launch_bounds__(256) void aggregate(
    const u16* __restrict__ Wb, const u16* __restrict__ xhb,
    const int* __restrict__ rowst, const int* __restrict__ deg,
    const int* __restrict__ eidw, const int* __restrict__ esrc,
    float* __restrict__ agg, int N) {
    const int w = threadIdx.x >> 6, lane = threadIdx.x & 63;
    const int n = blockIdx.x * 4 + w;
    if (n >= N) return;
    const int rs = rowst[n], d = deg[n];
    float a0 = 0.f, a1 = 0.f;
    for (int k = 0; k < d; ++k) {
        int e = eidw[rs + k], s = esrc[rs + k];
        u32 wp = *reinterpret_cast<const u32*>(&Wb[(size_t)e * 128 + lane * 2]);
        u32 xp = *reinterpret_cast<const u32*>(&xhb[(size_t)s * 128 + lane * 2]);
        a0 = fmaf(b2f_lo(xp), b2f_lo(wp), a0);
        a1 = fmaf(b2f_hi(xp), b2f_hi(wp), a1);
    }
    float2 r; r.x = a0; r.y = a1;
    *reinterpret_cast<float2*>(&agg[(size_t)n * 128 + lane * 2]) = r;
}

// ---------------------------------------------------------------------------
// Fallback (R1 path): fused edge kernel with f32 atomics
// ---------------------------------------------------------------------------
__global__ __launch_bounds__(256, 2) void edge_kernel(
    const float* __restrict__ basis, const float* __restrict__ e_ji,
    const int* __restrict__ pairs, const float* __restrict__ xh,
    const u16* __restrict__ fw1b, const u16* __restrict__ fw2b,
    const float* __restrict__ fb1, const float* __restrict__ fb2,
    float* __restrict__ agg, int E) {
    __shared__ u16 hb[64 * 136];
    __shared__ u16 fw1_lds[128 * 72];
    __shared__ u16 fw2_lds[128 * 136];
    __shared__ float cc[64];
    __shared__ int s_src[64];
    __shared__ int s_dst[64];

    const int tid = threadIdx.x;
    const int e0 = blockIdx.x * 64;

    for (int idx = tid; idx < 128 * 8; idx += 256) {
        int c = idx >> 3, kc = (idx & 7) * 8;
        *reinterpret_cast<uint4*>(&fw1_lds[c * 72 + kc]) =
            *reinterpret_cast<const uint4*>(&fw1b[c * 64 + kc]);
    }
    for (int idx = tid; idx < 128 * 16; idx += 256) {
        int c = idx >> 4, kc = (idx & 15) * 8;
        *reinterpret_cast<uint4*>(&fw2_lds[c * 136 + kc]) =
            *reinterpret_cast<const uint4*>(&fw2b[c * 128 + kc]);
    }
    for (int idx = tid; idx < 64 * 64; idx += 256) {
        int e = idx >> 6, k = idx & 63;
        int eg = e0 + e;
        float v = (k < 50 && eg < E) ? basis[(size_t)eg * 50 + k] : 0.0f;
        hb[e * 72 + k] = f2b(v);
    }
    if (tid < 64) {
        int eg = e0 + tid;
        if (eg < E) {
            cc[tid] = 0.25f * (__cosf(e_ji[eg] * 0.31415926535897932f) + 1.0f);
            s_src[tid] = pairs[eg];
            s_dst[tid] = pairs[E + eg];
        } else { cc[tid] = 0.0f; s_src[tid] = 0; s_dst[tid] = 0; }
    }
    __syncthreads();

    const int l = tid & 63, w = tid >> 6;
    const int lr = l & 15, lg = l >> 4;

    f32x4 acc1[8] = {};
    for (int ks = 0; ks < 2; ++ks) {
        bf16x8 a = *reinterpret_cast<const bf16x8*>(
            &hb[(w * 16 + lr) * 72 + ks * 32 + lg * 8]);
        for (int n = 0; n < 8; ++n) {
            bf16x8 b = *reinterpret_cast<const bf16x8*>(
                &fw1_lds[(n * 16 + lr) * 72 + ks * 32 + lg * 8]);
            acc1[n] = __builtin_amdgcn_mfma_f32_16x16x32_bf16(a, b, acc1[n], 0, 0, 0);
        }
    }
    __syncthreads();

    for (int n = 0; n < 8; ++n) {
        int c = n * 16 + lr;
        float bv = fb1[c];
        for (int i = 0; i < 4; ++i) {
            int r = w * 16 + lg * 4 + i;
            hb[r * 136 + c] = f2b(ssp(acc1[n][i] + bv));
        }
    }
    __syncthreads();

    f32x4 acc2[8] = {};
    for (int ks = 0; ks < 4; ++ks) {
        bf16x8 a = *reinterpret_cast<const bf16x8*>(
            &hb[(w * 16 + lr) * 136 + ks * 32 + lg * 8]);
        for (int n = 0; n < 8; ++n) {
            bf16x8 b = *reinterpret_cast<const bf16x8*>(
                &fw2_lds[(n * 16 + lr) * 136 + ks * 32 + lg * 8]);
            acc2[n] = __builtin_amdgcn_mfma_f32_16x16x32_bf16(a, b, acc2[n], 0, 0, 0);
        }
    }

    for (int n = 0; n < 8; ++n) {
        int c = n * 16 + lr;
        float bv = fb2[c];
        for (int i = 0; i < 4; ++i) {
            int eloc = w * 16 + lg * 4 + i;
            if (e0 + eloc < E) {
                float Wv = (acc2[n][i] + bv) * cc[eloc];
                float val = xh[(size_t)s_src[eloc] * 128 + c] * Wv;
                unsafeAtomicAdd(&agg[(size_t)s_dst[eloc] * 128 + c], val);
            }
        }
    }
}

extern "C" void kernel_launch(void* const* d_in, const int* in_sizes, int n_in,
                              void* d_out, int out_size, void* d_ws, size_t ws_size,
                              hipStream_t stream) {
    const float* x      = (const float*)d_in[0];
    const int*   pairs  = (const int*)d_in[1];
    const float* e_ji   = (const float*)d_in[2];
    const float* basis  = (const float*)d_in[3];
    const float* fw1    = (const float*)d_in[4];
    const float* fb1    = (const float*)d_in[5];
    const float* fw2    = (const float*)d_in[6];
    const float* fb2    = (const float*)d_in[7];
    const float* w1     = (const float*)d_in[8];
    const float* w2     = (const float*)d_in[9];
    const float* b2     = (const float*)d_in[10];
    const float* w3     = (const float*)d_in[11];
    const float* b3     = (const float*)d_in[12];
    float* out = (float*)d_out;

    const int N = in_sizes[0] / 128;
    const int E = in_sizes[2];
    const int nodeBlocks = (N + 63) / 64;
    const int nchunks = (N + 255) / 256;
    char* ws = (char*)d_ws;

    // CSR-path workspace layout
    size_t off = 0;
    auto nxt = [&](size_t bytes) {
        size_t o = off; off = (off + bytes + 255) & ~(size_t)255; return o;
    };
    u16*   Wb     = (u16*)  (ws + nxt((size_t)E * 128 * 2));
    u16*   xhb    = (u16*)  (ws + nxt((size_t)N * 128 * 2));
    float* agg    = (float*)(ws + nxt((size_t)N * 128 * 4));
    u16*   wb     = (u16*)  (ws + nxt(81920 * 2));
    int*   deg    = (int*)  (ws + nxt((size_t)N * 4));
    int*   incl   = (int*)  (ws + nxt((size_t)N * 4));
    int*   rowst  = (int*)  (ws + nxt((size_t)N * 4));
    int*   cursor = (int*)  (ws + nxt((size_t)N * 4));
    int*   bsum   = (int*)  (ws + nxt(1024));
    int*   eidw   = (int*)  (ws + nxt((size_t)E * 4));
    int*   esrc   = (int*)  (ws + nxt((size_t)E * 4));
    const size_t needed = off;

    const u16* fw1b = wb;
    const u16* fw2b = wb + 8192;
    const u16* w1b  = wb + 8192 + 16384;
    const u16* w2b  = wb + 8192 + 32768;
    const u16* w3b  = wb + 8192 + 49152;

    if (ws_size >= needed && nchunks <= 256) {
        prep_weights<<<288, 256, 0, stream>>>(fw1, fw2, w1, w2, w3, wb);
        hipMemsetAsync(deg, 0, (size_t)N * 4, stream);

        // xh (bf16) = x @ w1^T
        linear128<0, 1><<<nodeBlocks, 256, 0, stream>>>(x, w1b, nullptr, xhb, N);

        // CSR build
        hist_kernel<<<(E + 255) / 256, 256, 0, stream>>>(pairs, deg, E);
        scan_a<<<nchunks, 256, 0, stream>>>(deg, incl, bsum, N);
        scan_b<<<1, 256, 0, stream>>>(bsum, nchunks);
        scan_c<<<nchunks, 256, 0, stream>>>(incl, deg, bsum, rowst, cursor, N);
        fill_kernel<<<(E + 255) / 256, 256, 0, stream>>>(pairs, cursor, eidw, esrc, E);

        // filter MLP -> Wb
        edge_mlp<<<(E + 63) / 64, 256, 0, stream>>>(basis, e_ji, fw1b, fw2b,
                                                    fb1, fb2, Wb, E);
        // node-centric aggregation (no f32 atomics)
        aggregate<<<(N + 3) / 4, 256, 0, stream>>>(Wb, xhb, rowst, deg,
                                                   eidw, esrc, agg, N);

        linear128<1, 0><<<nodeBlocks, 256, 0, stream>>>(agg, w2b, b2, out, N);
        linear128<0, 0><<<nodeBlocks, 256, 0, stream>>>(out, w3b, b3, out, N);
    } else {
        // fallback: R1 atomic path (layout: xh f32 | agg | weights)
        const size_t nodeBytes = (size_t)N * 128 * sizeof(float);
        float* xhf   = (float*)ws;
        float* aggf  = (float*)(ws + nodeBytes);
        u16*   wbf   = (u16*)(ws + 2 * nodeBytes);
        const u16* ffw1b = wbf;
        const u16* ffw2b = wbf + 8192;
        const u16* fw1bw = wbf + 8192 + 16384;
        const u16* fw2bw = wbf + 8192 + 32768;
        const u16* fw3bw = wbf + 8192 + 49152;

        prep_weights<<<288, 256, 0, stream>>>(fw1, fw2, w1, w2, w3, wbf);
        hipMemsetAsync(aggf, 0, nodeBytes, stream);
        linear128<0, 0><<<nodeBlocks, 256, 0, stream>>>(x, fw1bw, nullptr, xhf, N);
        edge_kernel<<<(E + 63) / 64, 256, 0, stream>>>(basis, e_ji, pairs, xhf,
                                                       ffw1b, ffw2b, fb1, fb2, aggf, E);
        linear128<1, 0><<<nodeBlocks, 256, 0, stream>>>(aggf, fw2bw, b2, out, N);
        linear128<0, 0><<<nodeBlocks, 256, 0, stream>>>(out, fw3bw, b3, out, N);
    }
}

// Round 3
// 502.883 us; speedup vs baseline: 1.4716x; 1.2946x over previous
//
#include <hip/hip_runtime.h>

typedef float f32x4 __attribute__((ext_vector_type(4)));
typedef short bf16x8 __attribute__((ext_vector_type(8)));
typedef unsigned short u16;
typedef unsigned int u32;

// float -> bf16 bits, round-to-nearest-even
__device__ __forceinline__ u16 f2b(float f) {
    union { float f; u32 u; } v; v.f = f;
    u32 r = v.u + 0x7fffu + ((v.u >> 16) & 1u);
    return (u16)(r >> 16);
}
__device__ __forceinline__ u32 f2b_pk(float lo, float hi) {
    return (u32)f2b(lo) | ((u32)f2b(hi) << 16);
}
__device__ __forceinline__ float b2f_lo(u32 p) {
    union { u32 u; float f; } v; v.u = p << 16; return v.f;
}
__device__ __forceinline__ float b2f_hi(u32 p) {
    union { u32 u; float f; } v; v.u = p & 0xffff0000u; return v.f;
}

// shifted softplus via hw transcendentals (~7 VALU ops): log(1+e^x) - log2
__device__ __forceinline__ float ssp(float x) {
    return fmaxf(x, 0.0f) + __logf(1.0f + __expf(-fabsf(x))) - 0.6931471805599453f;
}

// ---------------------------------------------------------------------------
// Convert all weight matrices to bf16, layout [out_c][k] (fw1 K-padded 50->64)
// ---------------------------------------------------------------------------
__global__ void prep_weights(const float* __restrict__ fw1,
                             const float* __restrict__ fw2,
                             const float* __restrict__ w1,
                             const float* __restrict__ w2,
                             const float* __restrict__ w3,
                             u16* __restrict__ out) {
    int t = blockIdx.x * blockDim.x + threadIdx.x;
    if (t < 128 * 64) {
        int c = t >> 6, k = t & 63;
        out[t] = f2b(k < 50 ? fw1[c * 50 + k] : 0.0f);
        return;
    }
    t -= 128 * 64;
    if (t < 16384) { out[8192 + t] = f2b(fw2[t]); return; }
    t -= 16384;
    if (t < 16384) { out[8192 + 16384 + t] = f2b(w1[t]); return; }
    t -= 16384;
    if (t < 16384) { out[8192 + 32768 + t] = f2b(w2[t]); return; }
    t -= 16384;
    if (t < 16384) { out[8192 + 49152 + t] = f2b(w3[t]); return; }
}

// ---------------------------------------------------------------------------
// Generic out = act(in[M,128] @ wT + bias), bf16 MFMA 16x16x32.
// OBF=1 -> bf16 output, else f32.
// ---------------------------------------------------------------------------
template <int ACT, int OBF>
__global__ __launch_bounds__(256, 3) void linear128(
    const float* __restrict__ in, const u16* __restrict__ wb,
    const float* __restrict__ bias, void* __restrict__ outv, int M) {
    __shared__ u16 in_lds[64 * 136];
    __shared__ u16 w_lds[128 * 136];

    const int tid = threadIdx.x;
    const int r0 = blockIdx.x * 64;

    for (int idx = tid; idx < 128 * 16; idx += 256) {
        int c = idx >> 4, kc = (idx & 15) * 8;
        *reinterpret_cast<uint4*>(&w_lds[c * 136 + kc]) =
            *reinterpret_cast<const uint4*>(&wb[c * 128 + kc]);
    }
    for (int idx = tid; idx < 64 * 32; idx += 256) {
        int r = idx >> 5, kc = (idx & 31) * 4;
        int row = r0 + r;
        float4 v = make_float4(0.f, 0.f, 0.f, 0.f);
        if (row < M) v = *reinterpret_cast<const float4*>(&in[(size_t)row * 128 + kc]);
        u32* p = reinterpret_cast<u32*>(&in_lds[r * 136 + kc]);
        p[0] = f2b_pk(v.x, v.y); p[1] = f2b_pk(v.z, v.w);
    }
    __syncthreads();

    const int l = tid & 63, w = tid >> 6;
    const int lr = l & 15, lg = l >> 4;

    f32x4 acc[8] = {};
    for (int ks = 0; ks < 4; ++ks) {
        bf16x8 a = *reinterpret_cast<const bf16x8*>(
            &in_lds[(w * 16 + lr) * 136 + ks * 32 + lg * 8]);
        for (int n = 0; n < 8; ++n) {
            bf16x8 b = *reinterpret_cast<const bf16x8*>(
                &w_lds[(n * 16 + lr) * 136 + ks * 32 + lg * 8]);
            acc[n] = __builtin_amdgcn_mfma_f32_16x16x32_bf16(a, b, acc[n], 0, 0, 0);
        }
    }

    for (int n = 0; n < 8; ++n) {
        int c = n * 16 + lr;
        float bv = bias ? bias[c] : 0.0f;
        for (int i = 0; i < 4; ++i) {
            int row = r0 + w * 16 + lg * 4 + i;
            if (row < M) {
                float v = acc[n][i] + bv;
                if (ACT) v = ssp(v);
                if (OBF) ((u16*)outv)[(size_t)row * 128 + c] = f2b(v);
                else     ((float*)outv)[(size_t)row * 128 + c] = v;
            }
        }
    }
}

// ---------------------------------------------------------------------------
// Edge filter MLP, swapped-operand form.
//   mfma(a=weight rows, b=edge rows) -> D: col=edge (lane&15), row=channel.
//   Weights read as fragments directly from global (L1/L2-resident).
//   LDS: basis tile (stride 72) + h tile (stride 136) only.
// ---------------------------------------------------------------------------
__global__ __launch_bounds__(256) void edge_mlp(
    const float* __restrict__ basis, const float* __restrict__ e_ji,
    const u16* __restrict__ fw1b, const u16* __restrict__ fw2b,
    const float* __restrict__ fb1, const float* __restrict__ fb2,
    u16* __restrict__ Wb, int E) {
    __shared__ u16 bas[64 * 72];    // bf16 basis, K-padded 50->64
    __shared__ u16 hb[64 * 136];    // bf16 h

    const int tid = threadIdx.x;
    const int e0 = blockIdx.x * 64;

    // stage basis: 64 rows x 25 float2, coalesced, packed u32 LDS writes
    for (int idx = tid; idx < 64 * 25; idx += 256) {
        int e = idx / 25, p = idx - e * 25;
        int eg = e0 + e;
        float2 v = make_float2(0.f, 0.f);
        if (eg < E) v = *reinterpret_cast<const float2*>(&basis[(size_t)eg * 50 + 2 * p]);
        *reinterpret_cast<u32*>(&bas[e * 72 + 2 * p]) = f2b_pk(v.x, v.y);
    }
    // zero-pad k = 50..63
    for (int idx = tid; idx < 64 * 7; idx += 256) {
        int e = idx / 7, q = idx - e * 7;
        *reinterpret_cast<u32*>(&bas[e * 72 + 50 + 2 * q]) = 0u;
    }
    __syncthreads();

    const int l = tid & 63, w = tid >> 6;
    const int lr = l & 15, lg = l >> 4;
    const int erow = w * 16 + lr;          // this lane's edge (D column)

    // GEMM1: acc1[n] = fw1[ch tile n] x basis[edge tile]   (K=64)
    f32x4 acc1[8] = {};
    for (int ks = 0; ks < 2; ++ks) {
        bf16x8 b = *reinterpret_cast<const bf16x8*>(
            &bas[erow * 72 + ks * 32 + lg * 8]);
        for (int n = 0; n < 8; ++n) {
            bf16x8 a = *reinterpret_cast<const bf16x8*>(
                &fw1b[(size_t)(n * 16 + lr) * 64 + ks * 32 + lg * 8]);
            acc1[n] = __builtin_amdgcn_mfma_f32_16x16x32_bf16(a, b, acc1[n], 0, 0, 0);
        }
    }

    // h = ssp(acc1 + fb1): lane owns edge erow, channels n*16+lg*4+0..3
    for (int n = 0; n < 8; ++n) {
        float4 bv = *reinterpret_cast<const float4*>(&fb1[n * 16 + lg * 4]);
        u32 p0 = f2b_pk(ssp(acc1[n][0] + bv.x), ssp(acc1[n][1] + bv.y));
        u32 p1 = f2b_pk(ssp(acc1[n][2] + bv.z), ssp(acc1[n][3] + bv.w));
        u32* dst = reinterpret_cast<u32*>(&hb[erow * 136 + n * 16 + lg * 4]);
        dst[0] = p0; dst[1] = p1;          // ds_write_b64
    }
    // wave-internal LDS RAW only (own rows) -> no barrier needed

    // GEMM2: acc2[n] = fw2[ch tile n] x h[edge tile]   (K=128)
    f32x4 acc2[8] = {};
    for (int ks = 0; ks < 4; ++ks) {
        bf16x8 b = *reinterpret_cast<const bf16x8*>(
            &hb[erow * 136 + ks * 32 + lg * 8]);
        for (int n = 0; n < 8; ++n) {
            bf16x8 a = *reinterpret_cast<const bf16x8*>(
                &fw2b[(size_t)(n * 16 + lr) * 128 + ks * 32 + lg * 8]);
            acc2[n] = __builtin_amdgcn_mfma_f32_16x16x32_bf16(a, b, acc2[n], 0, 0, 0);
        }
    }

    // epilogue: W = (acc2 + fb2) * C(e); direct packed global store
    const int eg = e0 + erow;
    if (eg < E) {
        float cv = 0.25f * (__cosf(e_ji[eg] * 0.31415926535897932f) + 1.0f);
        for (int n = 0; n < 8; ++n) {
            float4 bv = *reinterpret_cast<const float4*>(&fb2[n * 16 + lg * 4]);
            uint2 pk;
            pk.x = f2b_pk((acc2[n][0] + bv.x) * cv, (acc2[n][1] + bv.y) * cv);
            pk.y = f2b_pk((acc2[n][2] + bv.z) * cv, (acc2[n][3] + bv.w) * cv);
            *reinterpret_cast<uint2*>(&Wb[(size_t)eg * 128 + n * 16 + lg * 4]) = pk;
        }
    }
}

// ---------------------------------------------------------------------------
// CSR build: histogram -> scan -> fill
// ---------------------------------------------------------------------------
__global__ void hist_kernel(const int* __restrict__ pairs, int* __restrict__ deg, int E) {
    int e = blockIdx.x * blockDim.x + threadIdx.x;
    if (e < E) atomicAdd(&deg[pairs[E + e]], 1);
}

__global__ void scan_a(const int* __restrict__ deg, int* __restrict__ incl,
                       int* __restrict__ bsum, int N) {
    __shared__ int s[256];
    int i = blockIdx.x * 256 + threadIdx.x;
    int v = (i < N) ? deg[i] : 0;
    s[threadIdx.x] = v; __syncthreads();
    for (int off = 1; off < 256; off <<= 1) {
        int t = (threadIdx.x >= off) ? s[threadIdx.x - off] : 0;
        __syncthreads();
        s[threadIdx.x] += t; __syncthreads();
    }
    if (i < N) incl[i] = s[threadIdx.x];
    if (threadIdx.x == 255) bsum[blockIdx.x] = s[255];
}

__global__ void scan_b(int* __restrict__ bsum, int nb) {
    __shared__ int s[256];
    int v = (threadIdx.x < nb) ? bsum[threadIdx.x] : 0;
    s[threadIdx.x] = v; __syncthreads();
    for (int off = 1; off < 256; off <<= 1) {
        int t = (threadIdx.x >= off) ? s[threadIdx.x - off] : 0;
        __syncthreads();
        s[threadIdx.x] += t; __syncthreads();
    }
    if (threadIdx.x < nb) bsum[threadIdx.x] = s[threadIdx.x] - v;  // exclusive
}

__global__ void scan_c(const int* __restrict__ incl, const int* __restrict__ deg,
                       const int* __restrict__ bsum, int* __restrict__ rowst,
                       int* __restrict__ cursor, int N) {
    int i = blockIdx.x * 256 + threadIdx.x;
    if (i < N) {
        int r = incl[i] - deg[i] + bsum[blockIdx.x];
        rowst[i] = r; cursor[i] = r;
    }
}

__global__ void fill_kernel(const int* __restrict__ pairs, int* __restrict__ cursor,
                            int* __restrict__ eidw, int* __restrict__ esrc, int E) {
    int e = blockIdx.x * blockDim.x + threadIdx.x;
    if (e < E) {
        int s = pairs[e], d = pairs[E + e];
        int pos = atomicAdd(&cursor[d], 1);
        eidw[pos] = e; esrc[pos] = s;
    }
}

// ---------------------------------------------------------------------------
// Aggregate: one wave per node, 2 cols/lane, register accumulation.
// ---------------------------------------------------------------------------
__global__ __launch_bounds__(256) void aggregate(
    const u16* __restrict__ Wb, const u16* __restrict__ xhb,
    const int* __restrict__ rowst, const int* __restrict__ deg,
    const int* __restrict__ eidw, const int* __restrict__ esrc,
    float* __restrict__ agg, int N) {
    const int w = threadIdx.x >> 6, lane = threadIdx.x & 63;
    const int n = blockIdx.x * 4 + w;
    if (n >= N) return;
    const int rs = rowst[n], d = deg[n];
    float a0 = 0.f, a1 = 0.f;
    for (int k = 0; k < d; ++k) {
        int e = eidw[rs + k], s = esrc[rs + k];
        u32 wp = *reinterpret_cast<const u32*>(&Wb[(size_t)e * 128 + lane * 2]);
        u32 xp = *reinterpret_cast<const u32*>(&xhb[(size_t)s * 128 + lane * 2]);
        a0 = fmaf(b2f_lo(xp), b2f_lo(wp), a0);
        a1 = fmaf(b2f_hi(xp), b2f_hi(wp), a1);
    }
    float2 r; r.x = a0; r.y = a1;
    *reinterpret_cast<float2*>(&agg[(size_t)n * 128 + lane * 2]) = r;
}

// ---------------------------------------------------------------------------
// Fallback (R1 path): fused edge kernel with f32 atomics
// ---------------------------------------------------------------------------
__global__ __launch_bounds__(256, 2) void edge_kernel(
    const float* __restrict__ basis, const float* __restrict__ e_ji,
    const int* __restrict__ pairs, const float* __restrict__ xh,
    const u16* __restrict__ fw1b, const u16* __restrict__ fw2b,
    const float* __restrict__ fb1, const float* __restrict__ fb2,
    float* __restrict__ agg, int E) {
    __shared__ u16 hb[64 * 136];
    __shared__ u16 fw1_lds[128 * 72];
    __shared__ u16 fw2_lds[128 * 136];
    __shared__ float cc[64];
    __shared__ int s_src[64];
    __shared__ int s_dst[64];

    const int tid = threadIdx.x;
    const int e0 = blockIdx.x * 64;

    for (int idx = tid; idx < 128 * 8; idx += 256) {
        int c = idx >> 3, kc = (idx & 7) * 8;
        *reinterpret_cast<uint4*>(&fw1_lds[c * 72 + kc]) =
            *reinterpret_cast<const uint4*>(&fw1b[c * 64 + kc]);
    }
    for (int idx = tid; idx < 128 * 16; idx += 256) {
        int c = idx >> 4, kc = (idx & 15) * 8;
        *reinterpret_cast<uint4*>(&fw2_lds[c * 136 + kc]) =
            *reinterpret_cast<const uint4*>(&fw2b[c * 128 + kc]);
    }
    for (int idx = tid; idx < 64 * 64; idx += 256) {
        int e = idx >> 6, k = idx & 63;
        int eg = e0 + e;
        float v = (k < 50 && eg < E) ? basis[(size_t)eg * 50 + k] : 0.0f;
        hb[e * 72 + k] = f2b(v);
    }
    if (tid < 64) {
        int eg = e0 + tid;
        if (eg < E) {
            cc[tid] = 0.25f * (__cosf(e_ji[eg] * 0.31415926535897932f) + 1.0f);
            s_src[tid] = pairs[eg];
            s_dst[tid] = pairs[E + eg];
        } else { cc[tid] = 0.0f; s_src[tid] = 0; s_dst[tid] = 0; }
    }
    __syncthreads();

    const int l = tid & 63, w = tid >> 6;
    const int lr = l & 15, lg = l >> 4;

    f32x4 acc1[8] = {};
    for (int ks = 0; ks < 2; ++ks) {
        bf16x8 a = *reinterpret_cast<const bf16x8*>(
            &hb[(w * 16 + lr) * 72 + ks * 32 + lg * 8]);
        for (int n = 0; n < 8; ++n) {
            bf16x8 b = *reinterpret_cast<const bf16x8*>(
                &fw1_lds[(n * 16 + lr) * 72 + ks * 32 + lg * 8]);
            acc1[n] = __builtin_amdgcn_mfma_f32_16x16x32_bf16(a, b, acc1[n], 0, 0, 0);
        }
    }
    __syncthreads();

    for (int n = 0; n < 8; ++n) {
        int c = n * 16 + lr;
        float bv = fb1[c];
        for (int i = 0; i < 4; ++i) {
            int r = w * 16 + lg * 4 + i;
            hb[r * 136 + c] = f2b(ssp(acc1[n][i] + bv));
        }
    }
    __syncthreads();

    f32x4 acc2[8] = {};
    for (int ks = 0; ks < 4; ++ks) {
        bf16x8 a = *reinterpret_cast<const bf16x8*>(
            &hb[(w * 16 + lr) * 136 + ks * 32 + lg * 8]);
        for (int n = 0; n < 8; ++n) {
            bf16x8 b = *reinterpret_cast<const bf16x8*>(
                &fw2_lds[(n * 16 + lr) * 136 + ks * 32 + lg * 8]);
            acc2[n] = __builtin_amdgcn_mfma_f32_16x16x32_bf16(a, b, acc2[n], 0, 0, 0);
        }
    }

    for (int n = 0; n < 8; ++n) {
        int c = n * 16 + lr;
        float bv = fb2[c];
        for (int i = 0; i < 4; ++i) {
            int eloc = w * 16 + lg * 4 + i;
            if (e0 + eloc < E) {
                float Wv = (acc2[n][i] + bv) * cc[eloc];
                float val = xh[(size_t)s_src[eloc] * 128 + c] * Wv;
                unsafeAtomicAdd(&agg[(size_t)s_dst[eloc] * 128 + c], val);
            }
        }
    }
}

extern "C" void kernel_launch(void* const* d_in, const int* in_sizes, int n_in,
                              void* d_out, int out_size, void* d_ws, size_t ws_size,
                              hipStream_t stream) {
    const float* x      = (const float*)d_in[0];
    const int*   pairs  = (const int*)d_in[1];
    const float* e_ji   = (const float*)d_in[2];
    const float* basis  = (const float*)d_in[3];
    const float* fw1    = (const float*)d_in[4];
    const float* fb1    = (const float*)d_in[5];
    const float* fw2    = (const float*)d_in[6];
    const float* fb2    = (const float*)d_in[7];
    const float* w1     = (const float*)d_in[8];
    const float* w2     = (const float*)d_in[9];
    const float* b2     = (const float*)d_in[10];
    const float* w3     = (const float*)d_in[11];
    const float* b3     = (const float*)d_in[12];
    float* out = (float*)d_out;

    const int N = in_sizes[0] / 128;
    const int E = in_sizes[2];
    const int nodeBlocks = (N + 63) / 64;
    const int nchunks = (N + 255) / 256;
    char* ws = (char*)d_ws;

    size_t off = 0;
    auto nxt = [&](size_t bytes) {
        size_t o = off; off = (off + bytes + 255) & ~(size_t)255; return o;
    };
    u16*   Wb     = (u16*)  (ws + nxt((size_t)E * 128 * 2));
    u16*   xhb    = (u16*)  (ws + nxt((size_t)N * 128 * 2));
    float* agg    = (float*)(ws + nxt((size_t)N * 128 * 4));
    u16*   wb     = (u16*)  (ws + nxt(81920 * 2));
    int*   deg    = (int*)  (ws + nxt((size_t)N * 4));
    int*   incl   = (int*)  (ws + nxt((size_t)N * 4));
    int*   rowst  = (int*)  (ws + nxt((size_t)N * 4));
    int*   cursor = (int*)  (ws + nxt((size_t)N * 4));
    int*   bsum   = (int*)  (ws + nxt(1024));
    int*   eidw   = (int*)  (ws + nxt((size_t)E * 4));
    int*   esrc   = (int*)  (ws + nxt((size_t)E * 4));
    const size_t needed = off;

    const u16* fw1b = wb;
    const u16* fw2b = wb + 8192;
    const u16* w1b  = wb + 8192 + 16384;
    const u16* w2b  = wb + 8192 + 32768;
    const u16* w3b  = wb + 8192 + 49152;

    if (ws_size >= needed && nchunks <= 256) {
        prep_weights<<<288, 256, 0, stream>>>(fw1, fw2, w1, w2, w3, wb);
        hipMemsetAsync(deg, 0, (size_t)N * 4, stream);

        linear128<0, 1><<<nodeBlocks, 256, 0, stream>>>(x, w1b, nullptr, xhb, N);

        hist_kernel<<<(E + 255) / 256, 256, 0, stream>>>(pairs, deg, E);
        scan_a<<<nchunks, 256, 0, stream>>>(deg, incl, bsum, N);
        scan_b<<<1, 256, 0, stream>>>(bsum, nchunks);
        scan_c<<<nchunks, 256, 0, stream>>>(incl, deg, bsum, rowst, cursor, N);
        fill_kernel<<<(E + 255) / 256, 256, 0, stream>>>(pairs, cursor, eidw, esrc, E);

        edge_mlp<<<(E + 63) / 64, 256, 0, stream>>>(basis, e_ji, fw1b, fw2b,
                                                    fb1, fb2, Wb, E);
        aggregate<<<(N + 3) / 4, 256, 0, stream>>>(Wb, xhb, rowst, deg,
                                                   eidw, esrc, agg, N);

        linear128<1, 0><<<nodeBlocks, 256, 0, stream>>>(agg, w2b, b2, out, N);
        linear128<0, 0><<<nodeBlocks, 256, 0, stream>>>(out, w3b, b3, out, N);
    } else {
        const size_t nodeBytes = (size_t)N * 128 * sizeof(float);
        float* xhf   = (float*)ws;
        float* aggf  = (float*)(ws + nodeBytes);
        u16*   wbf   = (u16*)(ws + 2 * nodeBytes);
        const u16* ffw1b = wbf;
        const u16* ffw2b = wbf + 8192;
        const u16* fw1bw = wbf + 8192 + 16384;
        const u16* fw2bw = wbf + 8192 + 32768;
        const u16* fw3bw = wbf + 8192 + 49152;

        prep_weights<<<288, 256, 0, stream>>>(fw1, fw2, w1, w2, w3, wbf);
        hipMemsetAsync(aggf, 0, nodeBytes, stream);
        linear128<0, 0><<<nodeBlocks, 256, 0, stream>>>(x, fw1bw, nullptr, xhf, N);
        edge_kernel<<<(E + 63) / 64, 256, 0, stream>>>(basis, e_ji, pairs, xhf,
                                                       ffw1b, ffw2b, fb1, fb2, aggf, E);
        linear128<1, 0><<<nodeBlocks, 256, 0, stream>>>(aggf, fw2bw, b2, out, N);
        linear128<0, 0><<<nodeBlocks, 256, 0, stream>>>(out, fw3bw, b3, out, N);
    }
}

// Round 4
// 411.332 us; speedup vs baseline: 1.7991x; 1.2226x over previous
//
#include <hip/hip_runtime.h>

typedef float f32x4 __attribute__((ext_vector_type(4)));
typedef short bf16x8 __attribute__((ext_vector_type(8)));
typedef unsigned short u16;
typedef unsigned int u32;

// float -> bf16 bits, round-to-nearest-even
__device__ __forceinline__ u16 f2b(float f) {
    union { float f; u32 u; } v; v.f = f;
    u32 r = v.u + 0x7fffu + ((v.u >> 16) & 1u);
    return (u16)(r >> 16);
}
__device__ __forceinline__ u32 f2b_pk(float lo, float hi) {
    return (u32)f2b(lo) | ((u32)f2b(hi) << 16);
}
__device__ __forceinline__ float b2f_lo(u32 p) {
    union { u32 u; float f; } v; v.u = p << 16; return v.f;
}
__device__ __forceinline__ float b2f_hi(u32 p) {
    union { u32 u; float f; } v; v.u = p & 0xffff0000u; return v.f;
}

// shifted softplus via hw transcendentals: log(1+e^x) - log2
__device__ __forceinline__ float ssp(float x) {
    return fmaxf(x, 0.0f) + __logf(1.0f + __expf(-fabsf(x))) - 0.6931471805599453f;
}

// ---------------------------------------------------------------------------
// Convert all weight matrices to bf16, layout [out_c][k] (fw1 K-padded 50->64)
// ---------------------------------------------------------------------------
__global__ void prep_weights(const float* __restrict__ fw1,
                             const float* __restrict__ fw2,
                             const float* __restrict__ w1,
                             const float* __restrict__ w2,
                             const float* __restrict__ w3,
                             u16* __restrict__ out) {
    int t = blockIdx.x * blockDim.x + threadIdx.x;
    if (t < 128 * 64) {
        int c = t >> 6, k = t & 63;
        out[t] = f2b(k < 50 ? fw1[c * 50 + k] : 0.0f);
        return;
    }
    t -= 128 * 64;
    if (t < 16384) { out[8192 + t] = f2b(fw2[t]); return; }
    t -= 16384;
    if (t < 16384) { out[8192 + 16384 + t] = f2b(w1[t]); return; }
    t -= 16384;
    if (t < 16384) { out[8192 + 32768 + t] = f2b(w2[t]); return; }
    t -= 16384;
    if (t < 16384) { out[8192 + 49152 + t] = f2b(w3[t]); return; }
}

// ---------------------------------------------------------------------------
// Generic out = act(in[M,128] @ wT + bias), bf16 MFMA 16x16x32.
// OBF=1 -> bf16 output, else f32.
// ---------------------------------------------------------------------------
template <int ACT, int OBF>
__global__ __launch_bounds__(256, 3) void linear128(
    const float* __restrict__ in, const u16* __restrict__ wb,
    const float* __restrict__ bias, void* __restrict__ outv, int M) {
    __shared__ u16 in_lds[64 * 136];
    __shared__ u16 w_lds[128 * 136];

    const int tid = threadIdx.x;
    const int r0 = blockIdx.x * 64;

    for (int idx = tid; idx < 128 * 16; idx += 256) {
        int c = idx >> 4, kc = (idx & 15) * 8;
        *reinterpret_cast<uint4*>(&w_lds[c * 136 + kc]) =
            *reinterpret_cast<const uint4*>(&wb[c * 128 + kc]);
    }
    for (int idx = tid; idx < 64 * 32; idx += 256) {
        int r = idx >> 5, kc = (idx & 31) * 4;
        int row = r0 + r;
        float4 v = make_float4(0.f, 0.f, 0.f, 0.f);
        if (row < M) v = *reinterpret_cast<const float4*>(&in[(size_t)row * 128 + kc]);
        u32* p = reinterpret_cast<u32*>(&in_lds[r * 136 + kc]);
        p[0] = f2b_pk(v.x, v.y); p[1] = f2b_pk(v.z, v.w);
    }
    __syncthreads();

    const int l = tid & 63, w = tid >> 6;
    const int lr = l & 15, lg = l >> 4;

    f32x4 acc[8] = {};
    for (int ks = 0; ks < 4; ++ks) {
        bf16x8 a = *reinterpret_cast<const bf16x8*>(
            &in_lds[(w * 16 + lr) * 136 + ks * 32 + lg * 8]);
        for (int n = 0; n < 8; ++n) {
            bf16x8 b = *reinterpret_cast<const bf16x8*>(
                &w_lds[(n * 16 + lr) * 136 + ks * 32 + lg * 8]);
            acc[n] = __builtin_amdgcn_mfma_f32_16x16x32_bf16(a, b, acc[n], 0, 0, 0);
        }
    }

    for (int n = 0; n < 8; ++n) {
        int c = n * 16 + lr;
        float bv = bias ? bias[c] : 0.0f;
        for (int i = 0; i < 4; ++i) {
            int row = r0 + w * 16 + lg * 4 + i;
            if (row < M) {
                float v = acc[n][i] + bv;
                if (ACT) v = ssp(v);
                if (OBF) ((u16*)outv)[(size_t)row * 128 + c] = f2b(v);
                else     ((float*)outv)[(size_t)row * 128 + c] = v;
            }
        }
    }
}

// ---------------------------------------------------------------------------
// Load one GEMM1 b-fragment (8 basis cols, f32->bf16) for edge row `row`.
// c0 in {0,8,16,24,32,40,48,56}; cols >= 50 are zero pad. float2 loads (8B
// aligned: row*50 even, c0 even).
// ---------------------------------------------------------------------------
__device__ __forceinline__ bf16x8 load_basis_frag(const float* __restrict__ basis,
                                                  int row, int c0, bool valid) {
    float v0 = 0.f, v1 = 0.f, v2 = 0.f, v3 = 0.f,
          v4 = 0.f, v5 = 0.f, v6 = 0.f, v7 = 0.f;
    if (valid && c0 < 50) {
        const float* p = &basis[(size_t)row * 50 + c0];
        if (c0 <= 42) {               // 8 valid cols
            float2 a = *reinterpret_cast<const float2*>(p);
            float2 b = *reinterpret_cast<const float2*>(p + 2);
            float2 c = *reinterpret_cast<const float2*>(p + 4);
            float2 d = *reinterpret_cast<const float2*>(p + 6);
            v0 = a.x; v1 = a.y; v2 = b.x; v3 = b.y;
            v4 = c.x; v5 = c.y; v6 = d.x; v7 = d.y;
        } else {                      // c0 == 48: 2 valid cols
            float2 a = *reinterpret_cast<const float2*>(p);
            v0 = a.x; v1 = a.y;
        }
    }
    bf16x8 r;
    u32* rp = reinterpret_cast<u32*>(&r);
    rp[0] = f2b_pk(v0, v1); rp[1] = f2b_pk(v2, v3);
    rp[2] = f2b_pk(v4, v5); rp[3] = f2b_pk(v6, v7);
    return r;
}

// ---------------------------------------------------------------------------
// Edge filter MLP v2: 128 edges/block, 4 waves x 32 edges (2 b-tiles/wave).
// Weight a-fragments from global (L1/L2-resident), amortized over 2 MFMAs.
// Basis b-fragments loaded per-lane directly from global (no staging LDS).
// No __syncthreads: each wave's hb rows are private.
// ---------------------------------------------------------------------------
__global__ __launch_bounds__(256) void edge_mlp(
    const float* __restrict__ basis, const float* __restrict__ e_ji,
    const u16* __restrict__ fw1b, const u16* __restrict__ fw2b,
    const float* __restrict__ fb1, const float* __restrict__ fb2,
    u16* __restrict__ Wb, int E) {
    __shared__ u16 hb[128 * 136];   // 34.8 KB, wave w owns rows w*32..w*32+31

    const int tid = threadIdx.x;
    const int l = tid & 63, w = tid >> 6;
    const int lr = l & 15, lg = l >> 4;
    const int e0 = blockIdx.x * 128;
    const int er0 = e0 + w * 32 + lr;          // tile-0 edge for this lane
    const int er1 = er0 + 16;                  // tile-1 edge
    const bool va0 = er0 < E, va1 = er1 < E;

    // GEMM1 b-fragments: basis rows, cols ks*32 + lg*8
    bf16x8 b0[2], b1[2];
#pragma unroll
    for (int ks = 0; ks < 2; ++ks) {
        int c0 = ks * 32 + lg * 8;
        b0[ks] = load_basis_frag(basis, er0, c0, va0);
        b1[ks] = load_basis_frag(basis, er1, c0, va1);
    }

    // GEMM1: acc1[t][n] over K=64
    f32x4 acc1[2][8] = {};
#pragma unroll
    for (int ks = 0; ks < 2; ++ks) {
#pragma unroll
        for (int n = 0; n < 8; ++n) {
            bf16x8 a = *reinterpret_cast<const bf16x8*>(
                &fw1b[(size_t)(n * 16 + lr) * 64 + ks * 32 + lg * 8]);
            acc1[0][n] = __builtin_amdgcn_mfma_f32_16x16x32_bf16(a, b0[ks], acc1[0][n], 0, 0, 0);
            acc1[1][n] = __builtin_amdgcn_mfma_f32_16x16x32_bf16(a, b1[ks], acc1[1][n], 0, 0, 0);
        }
    }

    // h = ssp(acc1 + fb1) -> hb (own rows; ds_write_b64)
    const int r0l = w * 32 + lr, r1l = r0l + 16;
#pragma unroll
    for (int n = 0; n < 8; ++n) {
        float4 bv = *reinterpret_cast<const float4*>(&fb1[n * 16 + lg * 4]);
        u32* d0 = reinterpret_cast<u32*>(&hb[r0l * 136 + n * 16 + lg * 4]);
        d0[0] = f2b_pk(ssp(acc1[0][n][0] + bv.x), ssp(acc1[0][n][1] + bv.y));
        d0[1] = f2b_pk(ssp(acc1[0][n][2] + bv.z), ssp(acc1[0][n][3] + bv.w));
        u32* d1 = reinterpret_cast<u32*>(&hb[r1l * 136 + n * 16 + lg * 4]);
        d1[0] = f2b_pk(ssp(acc1[1][n][0] + bv.x), ssp(acc1[1][n][1] + bv.y));
        d1[1] = f2b_pk(ssp(acc1[1][n][2] + bv.z), ssp(acc1[1][n][3] + bv.w));
    }
    // wave-internal LDS RAW only -> compiler lgkmcnt suffices, no barrier

    // GEMM2: acc2[t][n] over K=128
    f32x4 acc2[2][8] = {};
#pragma unroll
    for (int ks = 0; ks < 4; ++ks) {
        bf16x8 bb0 = *reinterpret_cast<const bf16x8*>(
            &hb[r0l * 136 + ks * 32 + lg * 8]);
        bf16x8 bb1 = *reinterpret_cast<const bf16x8*>(
            &hb[r1l * 136 + ks * 32 + lg * 8]);
#pragma unroll
        for (int n = 0; n < 8; ++n) {
            bf16x8 a = *reinterpret_cast<const bf16x8*>(
                &fw2b[(size_t)(n * 16 + lr) * 128 + ks * 32 + lg * 8]);
            acc2[0][n] = __builtin_amdgcn_mfma_f32_16x16x32_bf16(a, bb0, acc2[0][n], 0, 0, 0);
            acc2[1][n] = __builtin_amdgcn_mfma_f32_16x16x32_bf16(a, bb1, acc2[1][n], 0, 0, 0);
        }
    }

    // epilogue per tile: W = (acc2 + fb2) * C(e); packed 8B global stores
#pragma unroll
    for (int t = 0; t < 2; ++t) {
        int eg = t == 0 ? er0 : er1;
        bool va = t == 0 ? va0 : va1;
        if (va) {
            float cv = 0.25f * (__cosf(e_ji[eg] * 0.31415926535897932f) + 1.0f);
#pragma unroll
            for (int n = 0; n < 8; ++n) {
                float4 bv = *reinterpret_cast<const float4*>(&fb2[n * 16 + lg * 4]);
                uint2 pk;
                pk.x = f2b_pk((acc2[t][n][0] + bv.x) * cv, (acc2[t][n][1] + bv.y) * cv);
                pk.y = f2b_pk((acc2[t][n][2] + bv.z) * cv, (acc2[t][n][3] + bv.w) * cv);
                *reinterpret_cast<uint2*>(&Wb[(size_t)eg * 128 + n * 16 + lg * 4]) = pk;
            }
        }
    }
}

// ---------------------------------------------------------------------------
// CSR build: histogram -> scan -> fill
// ---------------------------------------------------------------------------
__global__ void hist_kernel(const int* __restrict__ pairs, int* __restrict__ deg, int E) {
    int e = blockIdx.x * blockDim.x + threadIdx.x;
    if (e < E) atomicAdd(&deg[pairs[E + e]], 1);
}

__global__ void scan_a(const int* __restrict__ deg, int* __restrict__ incl,
                       int* __restrict__ bsum, int N) {
    __shared__ int s[256];
    int i = blockIdx.x * 256 + threadIdx.x;
    int v = (i < N) ? deg[i] : 0;
    s[threadIdx.x] = v; __syncthreads();
    for (int off = 1; off < 256; off <<= 1) {
        int t = (threadIdx.x >= off) ? s[threadIdx.x - off] : 0;
        __syncthreads();
        s[threadIdx.x] += t; __syncthreads();
    }
    if (i < N) incl[i] = s[threadIdx.x];
    if (threadIdx.x == 255) bsum[blockIdx.x] = s[255];
}

__global__ void scan_b(int* __restrict__ bsum, int nb) {
    __shared__ int s[256];
    int v = (threadIdx.x < nb) ? bsum[threadIdx.x] : 0;
    s[threadIdx.x] = v; __syncthreads();
    for (int off = 1; off < 256; off <<= 1) {
        int t = (threadIdx.x >= off) ? s[threadIdx.x - off] : 0;
        __syncthreads();
        s[threadIdx.x] += t; __syncthreads();
    }
    if (threadIdx.x < nb) bsum[threadIdx.x] = s[threadIdx.x] - v;  // exclusive
}

__global__ void scan_c(const int* __restrict__ incl, const int* __restrict__ deg,
                       const int* __restrict__ bsum, int* __restrict__ rowst,
                       int* __restrict__ cursor, int N) {
    int i = blockIdx.x * 256 + threadIdx.x;
    if (i < N) {
        int r = incl[i] - deg[i] + bsum[blockIdx.x];
        rowst[i] = r; cursor[i] = r;
    }
}

__global__ void fill_kernel(const int* __restrict__ pairs, int* __restrict__ cursor,
                            int* __restrict__ eidw, int* __restrict__ esrc, int E) {
    int e = blockIdx.x * blockDim.x + threadIdx.x;
    if (e < E) {
        int s = pairs[e], d = pairs[E + e];
        int pos = atomicAdd(&cursor[d], 1);
        eidw[pos] = e; esrc[pos] = s;
    }
}

// ---------------------------------------------------------------------------
// Aggregate: one wave per node, 2 cols/lane, register accumulation.
// ---------------------------------------------------------------------------
__global__ __launch_bounds__(256) void aggregate(
    const u16* __restrict__ Wb, const u16* __restrict__ xhb,
    const int* __restrict__ rowst, const int* __restrict__ deg,
    const int* __restrict__ eidw, const int* __restrict__ esrc,
    float* __restrict__ agg, int N) {
    const int w = threadIdx.x >> 6, lane = threadIdx.x & 63;
    const int n = blockIdx.x * 4 + w;
    if (n >= N) return;
    const int rs = rowst[n], d = deg[n];
    float a0 = 0.f, a1 = 0.f;
    for (int k = 0; k < d; ++k) {
        int e = eidw[rs + k], s = esrc[rs + k];
        u32 wp = *reinterpret_cast<const u32*>(&Wb[(size_t)e * 128 + lane * 2]);
        u32 xp = *reinterpret_cast<const u32*>(&xhb[(size_t)s * 128 + lane * 2]);
        a0 = fmaf(b2f_lo(xp), b2f_lo(wp), a0);
        a1 = fmaf(b2f_hi(xp), b2f_hi(wp), a1);
    }
    float2 r; r.x = a0; r.y = a1;
    *reinterpret_cast<float2*>(&agg[(size_t)n * 128 + lane * 2]) = r;
}

// ---------------------------------------------------------------------------
// Fallback (R1 path): fused edge kernel with f32 atomics
// ---------------------------------------------------------------------------
__global__ __launch_bounds__(256, 2) void edge_kernel(
    const float* __restrict__ basis, const float* __restrict__ e_ji,
    const int* __restrict__ pairs, const float* __restrict__ xh,
    const u16* __restrict__ fw1b, const u16* __restrict__ fw2b,
    const float* __restrict__ fb1, const float* __restrict__ fb2,
    float* __restrict__ agg, int E) {
    __shared__ u16 hb[64 * 136];
    __shared__ u16 fw1_lds[128 * 72];
    __shared__ u16 fw2_lds[128 * 136];
    __shared__ float cc[64];
    __shared__ int s_src[64];
    __shared__ int s_dst[64];

    const int tid = threadIdx.x;
    const int e0 = blockIdx.x * 64;

    for (int idx = tid; idx < 128 * 8; idx += 256) {
        int c = idx >> 3, kc = (idx & 7) * 8;
        *reinterpret_cast<uint4*>(&fw1_lds[c * 72 + kc]) =
            *reinterpret_cast<const uint4*>(&fw1b[c * 64 + kc]);
    }
    for (int idx = tid; idx < 128 * 16; idx += 256) {
        int c = idx >> 4, kc = (idx & 15) * 8;
        *reinterpret_cast<uint4*>(&fw2_lds[c * 136 + kc]) =
            *reinterpret_cast<const uint4*>(&fw2b[c * 128 + kc]);
    }
    for (int idx = tid; idx < 64 * 64; idx += 256) {
        int e = idx >> 6, k = idx & 63;
        int eg = e0 + e;
        float v = (k < 50 && eg < E) ? basis[(size_t)eg * 50 + k] : 0.0f;
        hb[e * 72 + k] = f2b(v);
    }
    if (tid < 64) {
        int eg = e0 + tid;
        if (eg < E) {
            cc[tid] = 0.25f * (__cosf(e_ji[eg] * 0.31415926535897932f) + 1.0f);
            s_src[tid] = pairs[eg];
            s_dst[tid] = pairs[E + eg];
        } else { cc[tid] = 0.0f; s_src[tid] = 0; s_dst[tid] = 0; }
    }
    __syncthreads();

    const int l = tid & 63, w = tid >> 6;
    const int lr = l & 15, lg = l >> 4;

    f32x4 acc1[8] = {};
    for (int ks = 0; ks < 2; ++ks) {
        bf16x8 a = *reinterpret_cast<const bf16x8*>(
            &hb[(w * 16 + lr) * 72 + ks * 32 + lg * 8]);
        for (int n = 0; n < 8; ++n) {
            bf16x8 b = *reinterpret_cast<const bf16x8*>(
                &fw1_lds[(n * 16 + lr) * 72 + ks * 32 + lg * 8]);
            acc1[n] = __builtin_amdgcn_mfma_f32_16x16x32_bf16(a, b, acc1[n], 0, 0, 0);
        }
    }
    __syncthreads();

    for (int n = 0; n < 8; ++n) {
        int c = n * 16 + lr;
        float bv = fb1[c];
        for (int i = 0; i < 4; ++i) {
            int r = w * 16 + lg * 4 + i;
            hb[r * 136 + c] = f2b(ssp(acc1[n][i] + bv));
        }
    }
    __syncthreads();

    f32x4 acc2[8] = {};
    for (int ks = 0; ks < 4; ++ks) {
        bf16x8 a = *reinterpret_cast<const bf16x8*>(
            &hb[(w * 16 + lr) * 136 + ks * 32 + lg * 8]);
        for (int n = 0; n < 8; ++n) {
            bf16x8 b = *reinterpret_cast<const bf16x8*>(
                &fw2_lds[(n * 16 + lr) * 136 + ks * 32 + lg * 8]);
            acc2[n] = __builtin_amdgcn_mfma_f32_16x16x32_bf16(a, b, acc2[n], 0, 0, 0);
        }
    }

    for (int n = 0; n < 8; ++n) {
        int c = n * 16 + lr;
        float bv = fb2[c];
        for (int i = 0; i < 4; ++i) {
            int eloc = w * 16 + lg * 4 + i;
            if (e0 + eloc < E) {
                float Wv = (acc2[n][i] + bv) * cc[eloc];
                float val = xh[(size_t)s_src[eloc] * 128 + c] * Wv;
                unsafeAtomicAdd(&agg[(size_t)s_dst[eloc] * 128 + c], val);
            }
        }
    }
}

extern "C" void kernel_launch(void* const* d_in, const int* in_sizes, int n_in,
                              void* d_out, int out_size, void* d_ws, size_t ws_size,
                              hipStream_t stream) {
    const float* x      = (const float*)d_in[0];
    const int*   pairs  = (const int*)d_in[1];
    const float* e_ji   = (const float*)d_in[2];
    const float* basis  = (const float*)d_in[3];
    const float* fw1    = (const float*)d_in[4];
    const float* fb1    = (const float*)d_in[5];
    const float* fw2    = (const float*)d_in[6];
    const float* fb2    = (const float*)d_in[7];
    const float* w1     = (const float*)d_in[8];
    const float* w2     = (const float*)d_in[9];
    const float* b2     = (const float*)d_in[10];
    const float* w3     = (const float*)d_in[11];
    const float* b3     = (const float*)d_in[12];
    float* out = (float*)d_out;

    const int N = in_sizes[0] / 128;
    const int E = in_sizes[2];
    const int nodeBlocks = (N + 63) / 64;
    const int nchunks = (N + 255) / 256;
    char* ws = (char*)d_ws;

    size_t off = 0;
    auto nxt = [&](size_t bytes) {
        size_t o = off; off = (off + bytes + 255) & ~(size_t)255; return o;
    };
    u16*   Wb     = (u16*)  (ws + nxt((size_t)E * 128 * 2));
    u16*   xhb    = (u16*)  (ws + nxt((size_t)N * 128 * 2));
    float* agg    = (float*)(ws + nxt((size_t)N * 128 * 4));
    u16*   wb     = (u16*)  (ws + nxt(81920 * 2));
    int*   deg    = (int*)  (ws + nxt((size_t)N * 4));
    int*   incl   = (int*)  (ws + nxt((size_t)N * 4));
    int*   rowst  = (int*)  (ws + nxt((size_t)N * 4));
    int*   cursor = (int*)  (ws + nxt((size_t)N * 4));
    int*   bsum   = (int*)  (ws + nxt(1024));
    int*   eidw   = (int*)  (ws + nxt((size_t)E * 4));
    int*   esrc   = (int*)  (ws + nxt((size_t)E * 4));
    const size_t needed = off;

    const u16* fw1b = wb;
    const u16* fw2b = wb + 8192;
    const u16* w1b  = wb + 8192 + 16384;
    const u16* w2b  = wb + 8192 + 32768;
    const u16* w3b  = wb + 8192 + 49152;

    if (ws_size >= needed && nchunks <= 256) {
        prep_weights<<<288, 256, 0, stream>>>(fw1, fw2, w1, w2, w3, wb);
        hipMemsetAsync(deg, 0, (size_t)N * 4, stream);

        linear128<0, 1><<<nodeBlocks, 256, 0, stream>>>(x, w1b, nullptr, xhb, N);

        hist_kernel<<<(E + 255) / 256, 256, 0, stream>>>(pairs, deg, E);
        scan_a<<<nchunks, 256, 0, stream>>>(deg, incl, bsum, N);
        scan_b<<<1, 256, 0, stream>>>(bsum, nchunks);
        scan_c<<<nchunks, 256, 0, stream>>>(incl, deg, bsum, rowst, cursor, N);
        fill_kernel<<<(E + 255) / 256, 256, 0, stream>>>(pairs, cursor, eidw, esrc, E);

        edge_mlp<<<(E + 127) / 128, 256, 0, stream>>>(basis, e_ji, fw1b, fw2b,
                                                      fb1, fb2, Wb, E);
        aggregate<<<(N + 3) / 4, 256, 0, stream>>>(Wb, xhb, rowst, deg,
                                                   eidw, esrc, agg, N);

        linear128<1, 0><<<nodeBlocks, 256, 0, stream>>>(agg, w2b, b2, out, N);
        linear128<0, 0><<<nodeBlocks, 256, 0, stream>>>(out, w3b, b3, out, N);
    } else {
        const size_t nodeBytes = (size_t)N * 128 * sizeof(float);
        float* xhf   = (float*)ws;
        float* aggf  = (float*)(ws + nodeBytes);
        u16*   wbf   = (u16*)(ws + 2 * nodeBytes);
        const u16* ffw1b = wbf;
        const u16* ffw2b = wbf + 8192;
        const u16* fw1bw = wbf + 8192 + 16384;
        const u16* fw2bw = wbf + 8192 + 32768;
        const u16* fw3bw = wbf + 8192 + 49152;

        prep_weights<<<288, 256, 0, stream>>>(fw1, fw2, w1, w2, w3, wbf);
        hipMemsetAsync(aggf, 0, nodeBytes, stream);
        linear128<0, 0><<<nodeBlocks, 256, 0, stream>>>(x, fw1bw, nullptr, xhf, N);
        edge_kernel<<<(E + 63) / 64, 256, 0, stream>>>(basis, e_ji, pairs, xhf,
                                                       ffw1b, ffw2b, fb1, fb2, aggf, E);
        linear128<1, 0><<<nodeBlocks, 256, 0, stream>>>(aggf, fw2bw, b2, out, N);
        linear128<0, 0><<<nodeBlocks, 256, 0, stream>>>(out, fw3bw, b3, out, N);
    }
}